// Round 2
// baseline (1895.826 us; speedup 1.0000x reference)
//
#include <hip/hip_runtime.h>
#include <stdint.h>

#define NN 16384
#define FF 256
#define KK 8192

__device__ __forceinline__ uint32_t sortable_u32(float f) {
    uint32_t u = __float_as_uint(f);
    // monotone map: bigger float -> bigger uint
    return (u & 0x80000000u) ? ~u : (u | 0x80000000u);
}

// 1) scores = X @ sv ; build sortable u64 keys (score in high word,
//    ~row in low word -> descending order with lower-index tiebreak,
//    all keys globally distinct).
//    One wave per row: lane loads 4 consecutive floats (64*4 = 256 = FF).
__global__ __launch_bounds__(256) void scores_kernel(
        const float* __restrict__ X, const float* __restrict__ sv,
        uint64_t* __restrict__ keys) {
    const int wave = threadIdx.x >> 6;
    const int lane = threadIdx.x & 63;
    const int row  = blockIdx.x * 4 + wave;
    const float4 xv = *(const float4*)(X + (size_t)row * FF + lane * 4);
    const float4 s  = *(const float4*)(sv + lane * 4);
    float d = xv.x * s.x + xv.y * s.y + xv.z * s.z + xv.w * s.w;
    #pragma unroll
    for (int off = 32; off >= 1; off >>= 1) d += __shfl_down(d, off);
    if (lane == 0) {
        keys[row] = ((uint64_t)sortable_u32(d) << 32) | (uint32_t)(~row);
    }
}

// 2) rank[i] = #{ j : key_j > key_i } computed in full per thread (keys are
//    distinct, so rank is an exact permutation). Scatter idx[rank]=i directly;
//    no atomics, no rank array. keys[j] is block-uniform -> scalar loads.
__global__ __launch_bounds__(256) void rank_scatter_kernel(
        const uint64_t* __restrict__ keys, int* __restrict__ idx_int,
        float* __restrict__ out_idx) {
    const int i = blockIdx.x * 256 + threadIdx.x;
    const uint64_t ki = keys[i];
    int cnt = 0;
    #pragma unroll 8
    for (int j = 0; j < NN; ++j) {
        cnt += (keys[j] > ki) ? 1 : 0;
    }
    if (cnt < KK) {
        idx_int[cnt] = i;
        out_idx[cnt] = (float)i;
    }
}

// 3) X_pooled[r][:] = X[idx[r]][:]  — one wave per row, float4 both sides.
__global__ __launch_bounds__(256) void xgather_kernel(
        const float* __restrict__ X, const int* __restrict__ idx_int,
        float* __restrict__ outX) {
    const int wave = threadIdx.x >> 6;
    const int lane = threadIdx.x & 63;
    const int r = blockIdx.x * 4 + wave;
    const int src = idx_int[r];
    *(float4*)(outX + (size_t)r * FF + lane * 4) =
        *(const float4*)(X + (size_t)src * FF + lane * 4);
}

// 4) A_pooled[r][j] = A[idx[r]][idx[j]]
//    Stage full source row (64 KB) in LDS with coalesced float4 loads,
//    gather columns from LDS (indices held in registers), write coalesced
//    float4. 512 threads/block, 64 KB LDS -> 2 blocks/CU; inter-block
//    overlap pipelines the HBM stage phase against the LDS gather phase.
__global__ __launch_bounds__(512) void agather_kernel(
        const float* __restrict__ A, const int* __restrict__ idx_int,
        float* __restrict__ outA) {
    __shared__ float lds[NN];
    const int tid = threadIdx.x;

    // Each thread's 16 column indices, loaded once (int4 coalesced).
    int4 c[4];
    #pragma unroll
    for (int g = 0; g < 4; ++g)
        c[g] = *(const int4*)&idx_int[g * 2048 + tid * 4];

    #pragma unroll 1
    for (int rr = 0; rr < 16; ++rr) {
        const int r = blockIdx.x * 16 + rr;
        const int src = idx_int[r];              // block-uniform scalar load
        const float* __restrict__ arow = A + (size_t)src * NN;
        #pragma unroll
        for (int cb = 0; cb < NN; cb += 512 * 4) {
            *(float4*)&lds[cb + tid * 4] = *(const float4*)&arow[cb + tid * 4];
        }
        __syncthreads();
        float* __restrict__ orow = outA + (size_t)r * KK;
        #pragma unroll
        for (int g = 0; g < 4; ++g) {
            float4 o;
            o.x = lds[c[g].x];
            o.y = lds[c[g].y];
            o.z = lds[c[g].z];
            o.w = lds[c[g].w];
            *(float4*)&orow[g * 2048 + tid * 4] = o;
        }
        __syncthreads();
    }
}

extern "C" void kernel_launch(void* const* d_in, const int* in_sizes, int n_in,
                              void* d_out, int out_size, void* d_ws, size_t ws_size,
                              hipStream_t stream) {
    const float* X  = (const float*)d_in[0];
    const float* A  = (const float*)d_in[1];
    const float* sv = (const float*)d_in[2];

    float* out  = (float*)d_out;
    float* outX = out;                                   // KK*FF floats
    float* outA = out + (size_t)KK * FF;                 // KK*KK floats
    float* outI = outA + (size_t)KK * KK;                // KK floats

    char* ws = (char*)d_ws;
    uint64_t* keys   = (uint64_t*)ws;                    // 128 KB
    int*      idx_in = (int*)(ws + 131072);              // 32 KB

    scores_kernel      <<<NN / 4, 256, 0, stream>>>(X, sv, keys);
    rank_scatter_kernel<<<NN / 256, 256, 0, stream>>>(keys, idx_in, outI);
    xgather_kernel     <<<KK / 4, 256, 0, stream>>>(X, idx_in, outX);
    agather_kernel     <<<KK / 16, 512, 0, stream>>>(A, idx_in, outA);
}